// Round 1
// baseline (2753.669 us; speedup 1.0000x reference)
//
#include <hip/hip_runtime.h>
#include <hip/hip_bf16.h>

// Problem dims
#define B_   2
#define S_   50
#define AD_  32
#define D_   1024
#define H_   8
#define DH_  256
#define F_   4096
#define L_   6
#define P_   1024
#define T_   1074        // P + S
#define M_   100         // B*S tokens
#define NEGINF (-1e30f)

// ---------------- helpers ----------------
__device__ __forceinline__ float block_sum256(float v, volatile float* red) {
    #pragma unroll
    for (int off = 32; off > 0; off >>= 1) v += __shfl_down(v, off, 64);
    if ((threadIdx.x & 63) == 0) red[threadIdx.x >> 6] = v;
    __syncthreads();
    return red[0] + red[1] + red[2] + red[3];
}

__device__ __forceinline__ unsigned short f2bf(float x) {
    unsigned u = __float_as_uint(x);
    unsigned r = (u + 0x7fffu + ((u >> 16) & 1u)) >> 16;   // RNE
    return (unsigned short)r;
}

// ---------------- time embedding ----------------
// temb[b][i]: i<512 -> sin(t * 2pi/period_i), else cos;  period = 0.004*1000^(j/511)
__global__ __launch_bounds__(256) void k_temb(const float* __restrict__ ts, float* __restrict__ temb) {
    int idx = blockIdx.x * 256 + threadIdx.x;      // 2048
    int b = idx >> 10, i = idx & 1023, j = i & 511;
    float f = (float)j / 511.0f;
    float ang = ts[b] * 1570.7963267948966f * expf(-6.907755278982137f * f);
    temb[idx] = (i < 512) ? sinf(ang) : cosf(ang);
}

// ---------------- M=2 GEMV + bias + silu: out[b][n] = silu(sum_k A[b][k] W[k][n] + bias[n]) ----------------
__global__ __launch_bounds__(256) void k_gemv_silu(const float* __restrict__ A, const float* __restrict__ W,
                                                   const float* __restrict__ bias, float* __restrict__ out) {
    __shared__ float red[256 * 2];
    int lane = threadIdx.x & 63, ksub = threadIdx.x >> 6;
    int n = blockIdx.x * 64 + lane;
    float a0 = 0.f, a1 = 0.f;
    int kbase = ksub * 256;
    for (int kk = 0; kk < 256; kk++) {
        int k = kbase + kk;
        float w = W[(size_t)k * 1024 + n];
        a0 += A[k] * w;
        a1 += A[1024 + k] * w;
    }
    red[threadIdx.x * 2] = a0; red[threadIdx.x * 2 + 1] = a1;
    __syncthreads();
    if (ksub == 0) {
        float s0 = 0.f, s1 = 0.f;
        for (int j = 0; j < 4; j++) { s0 += red[(lane + 64 * j) * 2]; s1 += red[(lane + 64 * j) * 2 + 1]; }
        s0 += bias[n]; s1 += bias[n];
        out[n]        = s0 / (1.f + expf(-s0));
        out[1024 + n] = s1 / (1.f + expf(-s1));
    }
}

// ---------------- all adaRMS modulations: mods[job][b][3072] = cond[b] @ Wnorm_job ----------------
// job 0..5 = w_norm1[l], 6..11 = w_norm2[l], 12 = w_norm_f.  Atomic split-k (mods pre-zeroed).
__global__ __launch_bounds__(256) void k_mods(const float* __restrict__ cond, const float* __restrict__ wn1,
                                              const float* __restrict__ wn2, const float* __restrict__ wnf,
                                              float* __restrict__ mods) {
    int lane = threadIdx.x & 63, ksub = threadIdx.x >> 6;
    int n = blockIdx.x * 64 + lane;
    int job = blockIdx.y;
    const float* W = (job < 6)  ? wn1 + (size_t)job * D_ * 3072
                   : (job < 12) ? wn2 + (size_t)(job - 6) * D_ * 3072
                                : wnf;
    int k0 = blockIdx.z * 256 + ksub * 64;
    float a0 = 0.f, a1 = 0.f;
    for (int i = 0; i < 64; i++) {
        int k = k0 + i;
        float w = W[(size_t)k * 3072 + n];
        a0 += cond[k] * w;
        a1 += cond[D_ + k] * w;
    }
    atomicAdd(&mods[job * 6144 + n], a0);
    atomicAdd(&mods[job * 6144 + 3072 + n], a1);
}

// ---------------- h = x_t @ w_act_in + b ; normed = adaRMS(h, mods job0) ----------------
__global__ __launch_bounds__(256) void k_hinit(const float* __restrict__ x_t, const float* __restrict__ w_in,
                                               const float* __restrict__ b_in, const float* __restrict__ mods,
                                               float* __restrict__ h, float* __restrict__ normed) {
    __shared__ float xrow[AD_];
    __shared__ float red[4];
    int m = blockIdx.x;
    int b = m / S_;
    int n = threadIdx.x * 4;
    if (threadIdx.x < AD_) xrow[threadIdx.x] = x_t[m * AD_ + threadIdx.x];
    __syncthreads();
    float4 acc = *(const float4*)&b_in[n];
    #pragma unroll
    for (int k = 0; k < AD_; k++) {
        float x = xrow[k];
        const float4 w = *(const float4*)&w_in[(size_t)k * D_ + n];
        acc.x += x * w.x; acc.y += x * w.y; acc.z += x * w.z; acc.w += x * w.w;
    }
    *(float4*)&h[(size_t)m * D_ + n] = acc;
    float ss = acc.x * acc.x + acc.y * acc.y + acc.z * acc.z + acc.w * acc.w;
    float tot = block_sum256(ss, red);
    float rs = rsqrtf(tot / (float)D_ + 1e-6f);
    const float* md = mods + b * 3072;   // job 0
    float4 sc = *(const float4*)&md[n];
    float4 sh = *(const float4*)&md[1024 + n];
    float4 o;
    o.x = acc.x * rs * (1.f + sc.x) + sh.x;
    o.y = acc.y * rs * (1.f + sc.y) + sh.y;
    o.z = acc.z * rs * (1.f + sc.z) + sh.z;
    o.w = acc.w * rs * (1.f + sc.w) + sh.w;
    *(float4*)&normed[(size_t)m * D_ + n] = o;
}

// ---------------- generic split-K GEMM producing partials ----------------
// A (M_=100 x K), W row-major (K x SEG); Ntot cols across up to 3 weight segments.
// grid: (Ntot/256, 4 m-blocks of 28, K/256).  Block: 64 lanes (4 cols each) x 4 waves (7 rows each).
// part[kt][m][Ntot]
template<int SEG>
__global__ __launch_bounds__(256) void k_gemm(const float* __restrict__ A, int K,
                                              const float* __restrict__ W0, const float* __restrict__ W1,
                                              const float* __restrict__ W2, int Ntot, float* __restrict__ part) {
    __shared__ float a_lds[256 * 28];
    const int lane = threadIdx.x & 63;
    const int wv = threadIdx.x >> 6;
    const int n0 = blockIdx.x * 256;
    const int m0 = blockIdx.y * 28;
    const int k0 = blockIdx.z * 256;
    const int wi = n0 / SEG;
    const float* W = (wi == 0) ? W0 : ((wi == 1) ? W1 : W2);
    const int col = (n0 % SEG) + lane * 4;
    for (int i = threadIdx.x; i < 28 * 256; i += 256) {
        int m = i >> 8, k = i & 255;
        int gm = m0 + m;
        a_lds[k * 28 + m] = (gm < M_) ? A[(size_t)gm * K + k0 + k] : 0.f;
    }
    __syncthreads();
    float4 acc[7];
    #pragma unroll
    for (int i = 0; i < 7; i++) acc[i] = make_float4(0.f, 0.f, 0.f, 0.f);
    const float* Wp = W + (size_t)k0 * SEG + col;
    for (int kk = 0; kk < 256; kk++) {
        float4 w4 = *(const float4*)(Wp + (size_t)kk * SEG);
        const float* ap = &a_lds[kk * 28 + wv * 7];
        #pragma unroll
        for (int mi = 0; mi < 7; mi++) {
            float a = ap[mi];
            acc[mi].x += a * w4.x; acc[mi].y += a * w4.y; acc[mi].z += a * w4.z; acc[mi].w += a * w4.w;
        }
    }
    const int kt = blockIdx.z;
    #pragma unroll
    for (int mi = 0; mi < 7; mi++) {
        int gm = m0 + wv * 7 + mi;
        if (gm < M_)
            *(float4*)&part[((size_t)kt * M_ + gm) * Ntot + n0 + lane * 4] = acc[mi];
    }
}

// ---------------- QKV finish: reduce 4 partials, RoPE q/k (q also *1/16), scatter to (b,h,s,d) ----------------
__global__ __launch_bounds__(256) void k_qkv_fin(const float* __restrict__ part, float* __restrict__ q,
                                                 float* __restrict__ k, float* __restrict__ v) {
    int idx = blockIdx.x * 256 + threadIdx.x;   // 153600
    int e0 = idx * 4;
    int m = e0 / 6144, gcol = e0 % 6144;
    float4 s = make_float4(0.f, 0.f, 0.f, 0.f);
    #pragma unroll
    for (int kt = 0; kt < 4; kt++) {
        float4 p = *(const float4*)&part[((size_t)kt * M_ + m) * 6144 + gcol];
        s.x += p.x; s.y += p.y; s.z += p.z; s.w += p.w;
    }
    int sel = gcol >> 11, hc = gcol & 2047, hh = hc >> 8, d = hc & 255;
    int b = m / S_, si = m % S_;
    size_t outoff = ((size_t)((b * H_ + hh) * S_ + si)) * DH_ + d;
    if (sel == 2) { *(float4*)&v[outoff] = s; return; }
    int pcol = gcol + ((d < 128) ? 128 : -128);
    float4 p2 = make_float4(0.f, 0.f, 0.f, 0.f);
    #pragma unroll
    for (int kt = 0; kt < 4; kt++) {
        float4 p = *(const float4*)&part[((size_t)kt * M_ + m) * 6144 + pcol];
        p2.x += p.x; p2.y += p.y; p2.z += p.z; p2.w += p.w;
    }
    float sgn = (d < 128) ? -1.f : 1.f;
    float pos = (float)(P_ + si);
    float svv[4] = {s.x, s.y, s.z, s.w};
    float pvv[4] = {p2.x, p2.y, p2.z, p2.w};
    float o[4];
    #pragma unroll
    for (int j = 0; j < 4; j++) {
        int jj = (d + j) & 127;
        float invf = expf(-0.07195578415f * (float)jj);   // 10000^(-jj/128)
        float th = pos * invf;
        o[j] = svv[j] * cosf(th) + sgn * pvv[j] * sinf(th);
    }
    if (sel == 0) {
        *(float4*)&q[outoff] = make_float4(o[0] * 0.0625f, o[1] * 0.0625f, o[2] * 0.0625f, o[3] * 0.0625f);
    } else {
        *(float4*)&k[outoff] = make_float4(o[0], o[1], o[2], o[3]);
    }
}

// ---------------- flash-decode partial: chunked keys, online-softmax partials ----------------
#define CH_ 64
#define NC_ 17
__global__ __launch_bounds__(256) void k_flash(const float* __restrict__ kc, const float* __restrict__ vc,
                                               const float* __restrict__ qn, const float* __restrict__ kn,
                                               const float* __restrict__ vn,
                                               float* __restrict__ opart, float2* __restrict__ ml) {
    __shared__ __align__(16) char smem[64 * 258 * 2 + 50 * 258 * 2];
    unsigned short* k_l = (unsigned short*)smem;                 // bf16 K chunk [64][258]
    float* scb = (float*)smem;                                   // overlay: scores [50][68] (after phase1)
    unsigned short* q_l = (unsigned short*)(smem + 64 * 258 * 2); // bf16 Q [50][258]
    float* pT = (float*)(smem + 64 * 258 * 2);                   // overlay: p^T [64][52] (after phase1)
    int c = blockIdx.x, bh = blockIdx.y;
    int t0 = c * CH_;
    int nk = T_ - t0; if (nk > CH_) nk = CH_;
    const float* kcb = kc + (size_t)bh * P_ * DH_;
    const float* vcb = vc + (size_t)bh * P_ * DH_;
    for (int i = threadIdx.x; i < CH_ * DH_; i += 256) {
        int t = i >> 8, d = i & 255;
        int gt = t0 + t;
        float val = 0.f;
        if (gt < P_)      val = kcb[(size_t)gt * DH_ + d];
        else if (gt < T_) val = kn[((size_t)bh * S_ + (gt - P_)) * DH_ + d];
        k_l[t * 258 + d] = f2bf(val);
    }
    for (int i = threadIdx.x; i < S_ * DH_; i += 256) {
        int s = i >> 8, d = i & 255;
        q_l[s * 258 + d] = f2bf(qn[((size_t)bh * S_ + s) * DH_ + d]);
    }
    __syncthreads();
    // phase 1: scores.  200 active threads: (sg<25) x (tg<8); 2 queries x 8 keys each, packed-2 LDS reads.
    float acc[2][8];
    #pragma unroll
    for (int a = 0; a < 2; a++)
        #pragma unroll
        for (int j = 0; j < 8; j++) acc[a][j] = 0.f;
    int sg = threadIdx.x >> 3;
    int tg = threadIdx.x & 7;
    if (sg < 25) {
        const unsigned* q0p = (const unsigned*)(q_l + (2 * sg) * 258);
        const unsigned* q1p = (const unsigned*)(q_l + (2 * sg + 1) * 258);
        const unsigned* k0p = (const unsigned*)(k_l + (8 * tg) * 258);
        for (int dp = 0; dp < 128; dp++) {
            unsigned uq0 = q0p[dp], uq1 = q1p[dp];
            float q0a = __uint_as_float(uq0 << 16), q0b = __uint_as_float(uq0 & 0xffff0000u);
            float q1a = __uint_as_float(uq1 << 16), q1b = __uint_as_float(uq1 & 0xffff0000u);
            #pragma unroll
            for (int j = 0; j < 8; j++) {
                unsigned uk = k0p[j * 129 + dp];
                float ka = __uint_as_float(uk << 16), kb2 = __uint_as_float(uk & 0xffff0000u);
                acc[0][j] += q0a * ka; acc[0][j] += q0b * kb2;
                acc[1][j] += q1a * ka; acc[1][j] += q1b * kb2;
            }
        }
    }
    __syncthreads();   // done reading k_l/q_l bits we overwrite next
    if (sg < 25) {
        #pragma unroll
        for (int ss = 0; ss < 2; ss++) {
            int si = 2 * sg + ss;
            #pragma unroll
            for (int j = 0; j < 8; j++) {
                int tl = 8 * tg + j;
                int gt = t0 + tl;
                bool vis = (tl < nk) && ((gt < P_) || ((gt - P_) <= si));
                scb[si * 68 + tl] = vis ? acc[ss][j] : NEGINF;   // q pre-scaled by 1/16
            }
        }
    }
    __syncthreads();
    // phase 2: per-row chunk softmax -> p^T, (m,l) partials
    {
        int si = threadIdx.x;
        if (si < 52) {
            if (si < 50) {
                float mmax = NEGINF;
                for (int t = 0; t < CH_; t++) mmax = fmaxf(mmax, scb[si * 68 + t]);
                float lsum = 0.f;
                for (int t = 0; t < CH_; t++) {
                    float p = expf(scb[si * 68 + t] - mmax);
                    lsum += p;
                    pT[t * 52 + si] = p;
                }
                ml[((size_t)bh * NC_ + c) * S_ + si] = make_float2(mmax, lsum);
            } else {
                for (int t = 0; t < CH_; t++) pT[t * 52 + si] = 0.f;
            }
        }
    }
    __syncthreads();
    // phase 3: o_c[s][d] = sum_t p[s][t] V[t][d]; thread owns d
    {
        int d = threadIdx.x;
        float a3[50];
        #pragma unroll
        for (int i = 0; i < 50; i++) a3[i] = 0.f;
        for (int t = 0; t < nk; t++) {
            int gt = t0 + t;
            float vv = (gt < P_) ? vcb[(size_t)gt * DH_ + d]
                                 : vn[((size_t)bh * S_ + (gt - P_)) * DH_ + d];
            const float4* pr = (const float4*)(pT + t * 52);
            #pragma unroll
            for (int q4 = 0; q4 < 13; q4++) {
                float4 p = pr[q4];
                int sb = q4 * 4;
                a3[sb] += p.x * vv;
                a3[sb + 1] += p.y * vv;
                if (sb + 2 < 50) { a3[sb + 2] += p.z * vv; a3[sb + 3] += p.w * vv; }
            }
        }
        float* op = opart + ((size_t)bh * NC_ + c) * S_ * DH_ + d;
        #pragma unroll
        for (int s = 0; s < 50; s++) op[(size_t)s * DH_] = a3[s];
    }
}

// ---------------- combine chunk partials -> attn_out (b,s,h*dh) ----------------
__global__ __launch_bounds__(256) void k_att_combine(const float* __restrict__ opart, const float2* __restrict__ ml,
                                                     float* __restrict__ attnout) {
    int bh = blockIdx.x;
    int b = bh >> 3, hh = bh & 7;
    int d = threadIdx.x;
    for (int si = blockIdx.y * 10; si < blockIdx.y * 10 + 10; si++) {
        float mrun = NEGINF, lrun = 0.f, orun = 0.f;
        for (int c = 0; c < NC_; c++) {
            float2 mc = ml[((size_t)bh * NC_ + c) * S_ + si];
            float oc = opart[(((size_t)bh * NC_ + c) * S_ + si) * DH_ + d];
            if (mc.x > mrun) {
                float f = expf(mrun - mc.x);
                orun = orun * f + oc;
                lrun = lrun * f + mc.y;
                mrun = mc.x;
            } else {
                float f = expf(mc.x - mrun);
                orun += f * oc;
                lrun += f * mc.y;
            }
        }
        attnout[((size_t)(b * S_ + si)) * 2048 + hh * DH_ + d] = orun / lrun;
    }
}

// ---------------- residual finish: h += gate * sum_kt(part); normed = adaRMS(h, nmod) ----------------
__global__ __launch_bounds__(256) void k_resfin(const float* __restrict__ part, int KT,
                                                const float* __restrict__ gmod, const float* __restrict__ nmod,
                                                float* __restrict__ h, float* __restrict__ normed) {
    __shared__ float red[4];
    int m = blockIdx.x;
    int b = m / S_;
    int n = threadIdx.x * 4;
    float4 s = make_float4(0.f, 0.f, 0.f, 0.f);
    for (int kt = 0; kt < KT; kt++) {
        float4 p = *(const float4*)&part[((size_t)kt * M_ + m) * D_ + n];
        s.x += p.x; s.y += p.y; s.z += p.z; s.w += p.w;
    }
    float4 g = *(const float4*)&gmod[b * 3072 + 2048 + n];
    float4 hv = *(float4*)&h[(size_t)m * D_ + n];
    hv.x += g.x * s.x; hv.y += g.y * s.y; hv.z += g.z * s.z; hv.w += g.w * s.w;
    *(float4*)&h[(size_t)m * D_ + n] = hv;
    float ss = hv.x * hv.x + hv.y * hv.y + hv.z * hv.z + hv.w * hv.w;
    float tot = block_sum256(ss, red);
    float rs = rsqrtf(tot / (float)D_ + 1e-6f);
    float4 sc = *(const float4*)&nmod[b * 3072 + n];
    float4 sh = *(const float4*)&nmod[b * 3072 + 1024 + n];
    float4 o;
    o.x = hv.x * rs * (1.f + sc.x) + sh.x;
    o.y = hv.y * rs * (1.f + sc.y) + sh.y;
    o.z = hv.z * rs * (1.f + sc.z) + sh.z;
    o.w = hv.w * rs * (1.f + sc.w) + sh.w;
    *(float4*)&normed[(size_t)m * D_ + n] = o;
}

// ---------------- gate/up finish: act = gelu_tanh(g) * u ----------------
__global__ __launch_bounds__(256) void k_gufin(const float* __restrict__ part, float* __restrict__ act) {
    int idx = blockIdx.x * 256 + threadIdx.x;   // 102400
    int e0 = idx * 4;
    int m = e0 / F_, f = e0 % F_;
    float4 g = make_float4(0.f, 0.f, 0.f, 0.f), u = make_float4(0.f, 0.f, 0.f, 0.f);
    #pragma unroll
    for (int kt = 0; kt < 4; kt++) {
        const float* base = &part[((size_t)kt * M_ + m) * 8192];
        float4 pg = *(const float4*)&base[f];
        float4 pu = *(const float4*)&base[4096 + f];
        g.x += pg.x; g.y += pg.y; g.z += pg.z; g.w += pg.w;
        u.x += pu.x; u.y += pu.y; u.z += pu.z; u.w += pu.w;
    }
    float gv[4] = {g.x, g.y, g.z, g.w};
    float uv[4] = {u.x, u.y, u.z, u.w};
    float o[4];
    #pragma unroll
    for (int j = 0; j < 4; j++) {
        float x = gv[j];
        float t = tanhf(0.7978845608028654f * (x + 0.044715f * x * x * x));
        o[j] = 0.5f * x * (1.f + t) * uv[j];
    }
    *(float4*)&act[(size_t)m * F_ + f] = make_float4(o[0], o[1], o[2], o[3]);
}

// ---------------- final projection: out = normed_f @ w_act_out + b ----------------
__global__ __launch_bounds__(256) void k_final(const float* __restrict__ normed, const float* __restrict__ w,
                                               const float* __restrict__ bias, float* __restrict__ out) {
    int gid = blockIdx.x * 256 + threadIdx.x;
    if (gid >= M_ * AD_) return;
    int m = gid >> 5, n = gid & 31;
    float acc = bias[n];
    for (int k = 0; k < D_; k++) acc += normed[(size_t)m * D_ + k] * w[(size_t)k * AD_ + n];
    out[gid] = acc;
}

// ---------------- host launch ----------------
extern "C" void kernel_launch(void* const* d_in, const int* in_sizes, int n_in,
                              void* d_out, int out_size, void* d_ws, size_t ws_size,
                              hipStream_t stream) {
    (void)in_sizes; (void)n_in; (void)out_size; (void)ws_size;
    // d_in[0] = state (unused by reference)
    const float* x_t   = (const float*)d_in[1];
    const float* tstep = (const float*)d_in[2];
    const float* ck    = (const float*)d_in[3];
    const float* cv    = (const float*)d_in[4];
    const float* w_ti  = (const float*)d_in[5];
    const float* b_ti  = (const float*)d_in[6];
    const float* w_to  = (const float*)d_in[7];
    const float* b_to  = (const float*)d_in[8];
    const float* w_ai  = (const float*)d_in[9];
    const float* b_ai  = (const float*)d_in[10];
    const float* w_ao  = (const float*)d_in[11];
    const float* b_ao  = (const float*)d_in[12];
    const float* wq    = (const float*)d_in[13];
    const float* wk    = (const float*)d_in[14];
    const float* wv    = (const float*)d_in[15];
    const float* wo    = (const float*)d_in[16];
    const float* wg    = (const float*)d_in[17];
    const float* wu    = (const float*)d_in[18];
    const float* wd    = (const float*)d_in[19];
    const float* wn1   = (const float*)d_in[20];
    const float* wn2   = (const float*)d_in[21];
    const float* wnf   = (const float*)d_in[22];

    float* ws = (float*)d_ws;
    float* mods   = ws;                 // 13*6144      = 79872
    float* cond   = ws + 79872;         // 2048
    float* temb   = ws + 81920;         // 2048
    float* ubuf   = ws + 83968;         // 2048
    float* hbuf   = ws + 86016;         // 102400
    float* normed = ws + 188416;        // 102400
    float* qb     = ws + 290816;        // 204800
    float* kb     = ws + 495616;        // 204800
    float* vb     = ws + 700416;        // 204800
    float* opart  = ws + 905216;        // 17*16*50*256 = 3481600
    float* mlb    = ws + 4386816;       // 27200 (float2 per (bh,c,s))
    float* attno  = ws + 4414016;       // 204800
    float* act    = ws + 4618816;       // 409600
    float* gpart  = ws + 5028416;       // 3276800 scratch (max of all GEMM partials)
    // total = 8305216 floats = 33.2 MB

    hipMemsetAsync(mods, 0, (size_t)13 * 6144 * sizeof(float), stream);
    k_temb<<<8, 256, 0, stream>>>(tstep, temb);
    k_gemv_silu<<<16, 256, 0, stream>>>(temb, w_ti, b_ti, ubuf);
    k_gemv_silu<<<16, 256, 0, stream>>>(ubuf, w_to, b_to, cond);
    k_mods<<<dim3(48, 13, 4), 256, 0, stream>>>(cond, wn1, wn2, wnf, mods);
    k_hinit<<<100, 256, 0, stream>>>(x_t, w_ai, b_ai, mods, hbuf, normed);

    for (int l = 0; l < L_; l++) {
        k_gemm<2048><<<dim3(24, 4, 4), 256, 0, stream>>>(normed, 1024,
            wq + (size_t)l * 2097152, wk + (size_t)l * 2097152, wv + (size_t)l * 2097152, 6144, gpart);
        k_qkv_fin<<<600, 256, 0, stream>>>(gpart, qb, kb, vb);
        k_flash<<<dim3(NC_, 16), 256, 0, stream>>>(ck + (size_t)l * 4194304, cv + (size_t)l * 4194304,
            qb, kb, vb, opart, (float2*)mlb);
        k_att_combine<<<dim3(16, 5), 256, 0, stream>>>(opart, (const float2*)mlb, attno);
        k_gemm<1024><<<dim3(4, 4, 8), 256, 0, stream>>>(attno, 2048,
            wo + (size_t)l * 2097152, nullptr, nullptr, 1024, gpart);
        k_resfin<<<100, 256, 0, stream>>>(gpart, 8, mods + l * 6144, mods + (6 + l) * 6144, hbuf, normed);
        k_gemm<4096><<<dim3(32, 4, 4), 256, 0, stream>>>(normed, 1024,
            wg + (size_t)l * 4194304, wu + (size_t)l * 4194304, nullptr, 8192, gpart);
        k_gufin<<<400, 256, 0, stream>>>(gpart, act);
        k_gemm<1024><<<dim3(4, 4, 16), 256, 0, stream>>>(act, 4096,
            wd + (size_t)l * 4194304, nullptr, nullptr, 1024, gpart);
        k_resfin<<<100, 256, 0, stream>>>(gpart, 16, mods + (6 + l) * 6144,
            mods + ((l == 5) ? 12 : (l + 1)) * 6144, hbuf, normed);
    }
    k_final<<<13, 256, 0, stream>>>(normed, w_ao, b_ao, (float*)d_out);
}

// Round 2
// 2198.378 us; speedup vs baseline: 1.2526x; 1.2526x over previous
//
#include <hip/hip_runtime.h>
#include <hip/hip_bf16.h>

// Problem dims
#define B_   2
#define S_   50
#define AD_  32
#define D_   1024
#define H_   8
#define DH_  256
#define F_   4096
#define L_   6
#define P_   1024
#define T_   1074        // P + S
#define M_   100         // B*S tokens
#define NEGINF (-1e30f)

typedef __attribute__((ext_vector_type(8))) short short8;
typedef __attribute__((ext_vector_type(4))) float f32x4;

// ---------------- helpers ----------------
__device__ __forceinline__ float block_sum256(float v, volatile float* red) {
    #pragma unroll
    for (int off = 32; off > 0; off >>= 1) v += __shfl_down(v, off, 64);
    if ((threadIdx.x & 63) == 0) red[threadIdx.x >> 6] = v;
    __syncthreads();
    return red[0] + red[1] + red[2] + red[3];
}

__device__ __forceinline__ unsigned short f2bf(float x) {      // RNE
    unsigned u = __float_as_uint(x);
    unsigned r = (u + 0x7fffu + ((u >> 16) & 1u)) >> 16;
    return (unsigned short)r;
}
__device__ __forceinline__ float bf2f(unsigned short u) {
    return __uint_as_float(((unsigned)u) << 16);
}
// pack two fp32 -> two bf16 (truncate) in ONE v_perm_b32
__device__ __forceinline__ unsigned pack_bf(float lo, float hi) {
    return __builtin_amdgcn_perm(__float_as_uint(hi), __float_as_uint(lo), 0x07060302u);
}

// ---------------- time embedding ----------------
__global__ __launch_bounds__(256) void k_temb(const float* __restrict__ ts, float* __restrict__ temb) {
    int idx = blockIdx.x * 256 + threadIdx.x;      // 2048
    int b = idx >> 10, i = idx & 1023, j = i & 511;
    float f = (float)j / 511.0f;
    float ang = ts[b] * 1570.7963267948966f * expf(-6.907755278982137f * f);
    temb[idx] = (i < 512) ? sinf(ang) : cosf(ang);
}

// ---------------- M=2 GEMV + bias + silu ----------------
__global__ __launch_bounds__(256) void k_gemv_silu(const float* __restrict__ A, const float* __restrict__ W,
                                                   const float* __restrict__ bias, float* __restrict__ out) {
    __shared__ float red[256 * 2];
    int lane = threadIdx.x & 63, ksub = threadIdx.x >> 6;
    int n = blockIdx.x * 64 + lane;
    float a0 = 0.f, a1 = 0.f;
    int kbase = ksub * 256;
    for (int kk = 0; kk < 256; kk++) {
        int k = kbase + kk;
        float w = W[(size_t)k * 1024 + n];
        a0 += A[k] * w;
        a1 += A[1024 + k] * w;
    }
    red[threadIdx.x * 2] = a0; red[threadIdx.x * 2 + 1] = a1;
    __syncthreads();
    if (ksub == 0) {
        float s0 = 0.f, s1 = 0.f;
        for (int j = 0; j < 4; j++) { s0 += red[(lane + 64 * j) * 2]; s1 += red[(lane + 64 * j) * 2 + 1]; }
        s0 += bias[n]; s1 += bias[n];
        out[n]        = s0 / (1.f + expf(-s0));
        out[1024 + n] = s1 / (1.f + expf(-s1));
    }
}

// ---------------- all adaRMS modulations ----------------
__global__ __launch_bounds__(256) void k_mods(const float* __restrict__ cond, const float* __restrict__ wn1,
                                              const float* __restrict__ wn2, const float* __restrict__ wnf,
                                              float* __restrict__ mods) {
    int lane = threadIdx.x & 63, ksub = threadIdx.x >> 6;
    int n = blockIdx.x * 64 + lane;
    int job = blockIdx.y;
    const float* W = (job < 6)  ? wn1 + (size_t)job * D_ * 3072
                   : (job < 12) ? wn2 + (size_t)(job - 6) * D_ * 3072
                                : wnf;
    int k0 = blockIdx.z * 256 + ksub * 64;
    float a0 = 0.f, a1 = 0.f;
    for (int i = 0; i < 64; i++) {
        int k = k0 + i;
        float w = W[(size_t)k * 3072 + n];
        a0 += cond[k] * w;
        a1 += cond[D_ + k] * w;
    }
    atomicAdd(&mods[job * 6144 + n], a0);
    atomicAdd(&mods[job * 6144 + 3072 + n], a1);
}

// ---------------- h = x_t @ w_act_in + b ; normed(bf16) = adaRMS(h, job0) ----------------
__global__ __launch_bounds__(256) void k_hinit(const float* __restrict__ x_t, const float* __restrict__ w_in,
                                               const float* __restrict__ b_in, const float* __restrict__ mods,
                                               float* __restrict__ h, unsigned short* __restrict__ normed) {
    __shared__ float xrow[AD_];
    __shared__ float red[4];
    int m = blockIdx.x;
    int b = m / S_;
    int n = threadIdx.x * 4;
    if (threadIdx.x < AD_) xrow[threadIdx.x] = x_t[m * AD_ + threadIdx.x];
    __syncthreads();
    float4 acc = *(const float4*)&b_in[n];
    #pragma unroll
    for (int k = 0; k < AD_; k++) {
        float x = xrow[k];
        const float4 w = *(const float4*)&w_in[(size_t)k * D_ + n];
        acc.x += x * w.x; acc.y += x * w.y; acc.z += x * w.z; acc.w += x * w.w;
    }
    *(float4*)&h[(size_t)m * D_ + n] = acc;
    float ss = acc.x * acc.x + acc.y * acc.y + acc.z * acc.z + acc.w * acc.w;
    float tot = block_sum256(ss, red);
    float rs = rsqrtf(tot / (float)D_ + 1e-6f);
    const float* md = mods + b * 3072;
    float4 sc = *(const float4*)&md[n];
    float4 sh = *(const float4*)&md[1024 + n];
    ushort4 o;
    o.x = f2bf(acc.x * rs * (1.f + sc.x) + sh.x);
    o.y = f2bf(acc.y * rs * (1.f + sc.y) + sh.y);
    o.z = f2bf(acc.z * rs * (1.f + sc.z) + sh.z);
    o.w = f2bf(acc.w * rs * (1.f + sc.w) + sh.w);
    *(ushort4*)&normed[(size_t)m * D_ + n] = o;
}

// ---------------- bf16 MFMA GEMM ----------------
// A: bf16 [M_][K] (rows >= M_ zero-padded in staging). W: fp32 [K][SEG] x up-to-3 segments.
// Block tile: M=112 x N=128, full Ksplit range. grid = (Ntot/128, 1, K/Ksplit).
// Output: part[kt][m][Ntot] fp32.
#define BM 112
#define BN 128
#define BKg 64
#define LDA 72
#define LDB 72
template<int SEG>
__global__ __launch_bounds__(256) void k_gemm_bf(const unsigned short* __restrict__ A, int K, int Ksplit,
        const float* __restrict__ W0, const float* __restrict__ W1, const float* __restrict__ W2,
        int Ntot, float* __restrict__ part) {
    __shared__ unsigned short Alds[BM * LDA];   // 16128 B
    __shared__ unsigned short Blds[BN * LDB];   // 18432 B
    const int tid = threadIdx.x;
    const int lane = tid & 63;
    const int wv = tid >> 6;
    const int l16 = lane & 15, l4 = lane >> 4;
    const int n0 = blockIdx.x * BN;
    const int wi = n0 / SEG;
    const float* W = (wi == 0) ? W0 : ((wi == 1) ? W1 : W2);
    const int nseg = n0 % SEG;
    const int kbase = blockIdx.z * Ksplit;

    f32x4 acc[7][2];
    #pragma unroll
    for (int mi = 0; mi < 7; mi++)
        #pragma unroll
        for (int ni = 0; ni < 2; ni++) acc[mi][ni] = (f32x4){0.f, 0.f, 0.f, 0.f};

    const int bkc = (tid >> 5) * 8;          // B-stage k-chunk 0..56
    const int bn4 = (tid & 31) * 4;          // B-stage n-group

    for (int k0 = 0; k0 < Ksplit; k0 += BKg) {
        // stage A: 112 rows x 64 k, bf16 copy (16B per thread-chunk)
        for (int i = tid; i < BM * 8; i += 256) {
            int r = i >> 3, kc = (i & 7) * 8;
            uint4 val = make_uint4(0u, 0u, 0u, 0u);
            if (r < M_) val = *(const uint4*)&A[(size_t)r * K + kbase + k0 + kc];
            *(uint4*)&Alds[r * LDA + kc] = val;
        }
        // stage B: 64k x 128n fp32 -> bf16, LDS layout [n][k]
        {
            float4 wv4[8];
            #pragma unroll
            for (int q = 0; q < 8; q++)
                wv4[q] = *(const float4*)&W[(size_t)(kbase + k0 + bkc + q) * SEG + nseg + bn4];
            #define PACK_ROW(J, COMP) { \
                uint4 pk; \
                pk.x = pack_bf(wv4[0].COMP, wv4[1].COMP); \
                pk.y = pack_bf(wv4[2].COMP, wv4[3].COMP); \
                pk.z = pack_bf(wv4[4].COMP, wv4[5].COMP); \
                pk.w = pack_bf(wv4[6].COMP, wv4[7].COMP); \
                *(uint4*)&Blds[(bn4 + J) * LDB + bkc] = pk; }
            PACK_ROW(0, x) PACK_ROW(1, y) PACK_ROW(2, z) PACK_ROW(3, w)
            #undef PACK_ROW
        }
        __syncthreads();
        #pragma unroll
        for (int kb = 0; kb < 2; kb++) {
            short8 bf0 = *(const short8*)&Blds[(wv * 32 + 0 * 16 + l16) * LDB + kb * 32 + l4 * 8];
            short8 bf1 = *(const short8*)&Blds[(wv * 32 + 1 * 16 + l16) * LDB + kb * 32 + l4 * 8];
            #pragma unroll
            for (int mi = 0; mi < 7; mi++) {
                short8 af = *(const short8*)&Alds[(mi * 16 + l16) * LDA + kb * 32 + l4 * 8];
                acc[mi][0] = __builtin_amdgcn_mfma_f32_16x16x32_bf16(af, bf0, acc[mi][0], 0, 0, 0);
                acc[mi][1] = __builtin_amdgcn_mfma_f32_16x16x32_bf16(af, bf1, acc[mi][1], 0, 0, 0);
            }
        }
        __syncthreads();
    }
    float* pbase = part + (size_t)blockIdx.z * M_ * Ntot;
    #pragma unroll
    for (int mi = 0; mi < 7; mi++) {
        #pragma unroll
        for (int ni = 0; ni < 2; ni++) {
            int col = n0 + wv * 32 + ni * 16 + l16;
            #pragma unroll
            for (int r = 0; r < 4; r++) {
                int row = mi * 16 + l4 * 4 + r;
                if (row < M_) pbase[(size_t)row * Ntot + col] = acc[mi][ni][r];
            }
        }
    }
}

// ---------------- QKV finish: reduce KT=2 partials, RoPE q/k, scatter ----------------
__global__ __launch_bounds__(256) void k_qkv_fin(const float* __restrict__ part, float* __restrict__ q,
                                                 float* __restrict__ k, float* __restrict__ v) {
    int idx = blockIdx.x * 256 + threadIdx.x;   // 153600
    int e0 = idx * 4;
    int m = e0 / 6144, gcol = e0 % 6144;
    float4 s = make_float4(0.f, 0.f, 0.f, 0.f);
    #pragma unroll
    for (int kt = 0; kt < 2; kt++) {
        float4 p = *(const float4*)&part[((size_t)kt * M_ + m) * 6144 + gcol];
        s.x += p.x; s.y += p.y; s.z += p.z; s.w += p.w;
    }
    int sel = gcol >> 11, hc = gcol & 2047, hh = hc >> 8, d = hc & 255;
    int b = m / S_, si = m % S_;
    size_t outoff = ((size_t)((b * H_ + hh) * S_ + si)) * DH_ + d;
    if (sel == 2) { *(float4*)&v[outoff] = s; return; }
    int pcol = gcol + ((d < 128) ? 128 : -128);
    float4 p2 = make_float4(0.f, 0.f, 0.f, 0.f);
    #pragma unroll
    for (int kt = 0; kt < 2; kt++) {
        float4 p = *(const float4*)&part[((size_t)kt * M_ + m) * 6144 + pcol];
        p2.x += p.x; p2.y += p.y; p2.z += p.z; p2.w += p.w;
    }
    float sgn = (d < 128) ? -1.f : 1.f;
    float pos = (float)(P_ + si);
    float svv[4] = {s.x, s.y, s.z, s.w};
    float pvv[4] = {p2.x, p2.y, p2.z, p2.w};
    float o[4];
    #pragma unroll
    for (int j = 0; j < 4; j++) {
        int jj = (d + j) & 127;
        float invf = expf(-0.07195578415f * (float)jj);   // 10000^(-jj/128)
        float th = pos * invf;
        o[j] = svv[j] * cosf(th) + sgn * pvv[j] * sinf(th);
    }
    if (sel == 0) {
        *(float4*)&q[outoff] = make_float4(o[0] * 0.0625f, o[1] * 0.0625f, o[2] * 0.0625f, o[3] * 0.0625f);
    } else {
        *(float4*)&k[outoff] = make_float4(o[0], o[1], o[2], o[3]);
    }
}

// ---------------- flash-decode partial ----------------
#define CH_ 64
#define NC_ 17
__global__ __launch_bounds__(256) void k_flash(const float* __restrict__ kc, const float* __restrict__ vc,
                                               const float* __restrict__ qn, const float* __restrict__ kn,
                                               const float* __restrict__ vn,
                                               float* __restrict__ opart, float2* __restrict__ ml) {
    __shared__ __align__(16) char smem[64 * 258 * 2 + 50 * 258 * 2];
    unsigned short* k_l = (unsigned short*)smem;
    float* scb = (float*)smem;
    unsigned short* q_l = (unsigned short*)(smem + 64 * 258 * 2);
    float* pT = (float*)(smem + 64 * 258 * 2);
    int c = blockIdx.x, bh = blockIdx.y;
    int t0 = c * CH_;
    int nk = T_ - t0; if (nk > CH_) nk = CH_;
    const float* kcb = kc + (size_t)bh * P_ * DH_;
    const float* vcb = vc + (size_t)bh * P_ * DH_;
    for (int i = threadIdx.x; i < CH_ * DH_; i += 256) {
        int t = i >> 8, d = i & 255;
        int gt = t0 + t;
        float val = 0.f;
        if (gt < P_)      val = kcb[(size_t)gt * DH_ + d];
        else if (gt < T_) val = kn[((size_t)bh * S_ + (gt - P_)) * DH_ + d];
        k_l[t * 258 + d] = f2bf(val);
    }
    for (int i = threadIdx.x; i < S_ * DH_; i += 256) {
        int s = i >> 8, d = i & 255;
        q_l[s * 258 + d] = f2bf(qn[((size_t)bh * S_ + s) * DH_ + d]);
    }
    __syncthreads();
    float acc[2][8];
    #pragma unroll
    for (int a = 0; a < 2; a++)
        #pragma unroll
        for (int j = 0; j < 8; j++) acc[a][j] = 0.f;
    int sg = threadIdx.x >> 3;
    int tg = threadIdx.x & 7;
    if (sg < 25) {
        const unsigned* q0p = (const unsigned*)(q_l + (2 * sg) * 258);
        const unsigned* q1p = (const unsigned*)(q_l + (2 * sg + 1) * 258);
        const unsigned* k0p = (const unsigned*)(k_l + (8 * tg) * 258);
        for (int dp = 0; dp < 128; dp++) {
            unsigned uq0 = q0p[dp], uq1 = q1p[dp];
            float q0a = __uint_as_float(uq0 << 16), q0b = __uint_as_float(uq0 & 0xffff0000u);
            float q1a = __uint_as_float(uq1 << 16), q1b = __uint_as_float(uq1 & 0xffff0000u);
            #pragma unroll
            for (int j = 0; j < 8; j++) {
                unsigned uk = k0p[j * 129 + dp];
                float ka = __uint_as_float(uk << 16), kb2 = __uint_as_float(uk & 0xffff0000u);
                acc[0][j] += q0a * ka; acc[0][j] += q0b * kb2;
                acc[1][j] += q1a * ka; acc[1][j] += q1b * kb2;
            }
        }
    }
    __syncthreads();
    if (sg < 25) {
        #pragma unroll
        for (int ss = 0; ss < 2; ss++) {
            int si = 2 * sg + ss;
            #pragma unroll
            for (int j = 0; j < 8; j++) {
                int tl = 8 * tg + j;
                int gt = t0 + tl;
                bool vis = (tl < nk) && ((gt < P_) || ((gt - P_) <= si));
                scb[si * 68 + tl] = vis ? acc[ss][j] : NEGINF;
            }
        }
    }
    __syncthreads();
    {
        int si = threadIdx.x;
        if (si < 52) {
            if (si < 50) {
                float mmax = NEGINF;
                for (int t = 0; t < CH_; t++) mmax = fmaxf(mmax, scb[si * 68 + t]);
                float lsum = 0.f;
                for (int t = 0; t < CH_; t++) {
                    float p = expf(scb[si * 68 + t] - mmax);
                    lsum += p;
                    pT[t * 52 + si] = p;
                }
                ml[((size_t)bh * NC_ + c) * S_ + si] = make_float2(mmax, lsum);
            } else {
                for (int t = 0; t < CH_; t++) pT[t * 52 + si] = 0.f;
            }
        }
    }
    __syncthreads();
    {
        int d = threadIdx.x;
        float a3[50];
        #pragma unroll
        for (int i = 0; i < 50; i++) a3[i] = 0.f;
        for (int t = 0; t < nk; t++) {
            int gt = t0 + t;
            float vv = (gt < P_) ? vcb[(size_t)gt * DH_ + d]
                                 : vn[((size_t)bh * S_ + (gt - P_)) * DH_ + d];
            const float4* pr = (const float4*)(pT + t * 52);
            #pragma unroll
            for (int q4 = 0; q4 < 13; q4++) {
                float4 p = pr[q4];
                int sb = q4 * 4;
                a3[sb] += p.x * vv;
                a3[sb + 1] += p.y * vv;
                if (sb + 2 < 50) { a3[sb + 2] += p.z * vv; a3[sb + 3] += p.w * vv; }
            }
        }
        float* op = opart + ((size_t)bh * NC_ + c) * S_ * DH_ + d;
        #pragma unroll
        for (int s = 0; s < 50; s++) op[(size_t)s * DH_] = a3[s];
    }
}

// ---------------- combine chunk partials -> attn_out bf16 (b,s,h*dh) ----------------
__global__ __launch_bounds__(256) void k_att_combine(const float* __restrict__ opart, const float2* __restrict__ ml,
                                                     unsigned short* __restrict__ attnout) {
    int bh = blockIdx.x;
    int b = bh >> 3, hh = bh & 7;
    int d = threadIdx.x;
    for (int si = blockIdx.y * 10; si < blockIdx.y * 10 + 10; si++) {
        float mrun = NEGINF, lrun = 0.f, orun = 0.f;
        for (int c = 0; c < NC_; c++) {
            float2 mc = ml[((size_t)bh * NC_ + c) * S_ + si];
            float oc = opart[(((size_t)bh * NC_ + c) * S_ + si) * DH_ + d];
            if (mc.x > mrun) {
                float f = expf(mrun - mc.x);
                orun = orun * f + oc;
                lrun = lrun * f + mc.y;
                mrun = mc.x;
            } else {
                float f = expf(mc.x - mrun);
                orun += f * oc;
                lrun += f * mc.y;
            }
        }
        attnout[((size_t)(b * S_ + si)) * 2048 + hh * DH_ + d] = f2bf(orun / lrun);
    }
}

// ---------------- residual finish: h += gate * sum_kt(part); normed(bf16) = adaRMS(h, nmod) ----------------
__global__ __launch_bounds__(256) void k_resfin(const float* __restrict__ part, int KT,
                                                const float* __restrict__ gmod, const float* __restrict__ nmod,
                                                float* __restrict__ h, unsigned short* __restrict__ normed) {
    __shared__ float red[4];
    int m = blockIdx.x;
    int b = m / S_;
    int n = threadIdx.x * 4;
    float4 s = make_float4(0.f, 0.f, 0.f, 0.f);
    for (int kt = 0; kt < KT; kt++) {
        float4 p = *(const float4*)&part[((size_t)kt * M_ + m) * D_ + n];
        s.x += p.x; s.y += p.y; s.z += p.z; s.w += p.w;
    }
    float4 g = *(const float4*)&gmod[b * 3072 + 2048 + n];
    float4 hv = *(float4*)&h[(size_t)m * D_ + n];
    hv.x += g.x * s.x; hv.y += g.y * s.y; hv.z += g.z * s.z; hv.w += g.w * s.w;
    *(float4*)&h[(size_t)m * D_ + n] = hv;
    float ss = hv.x * hv.x + hv.y * hv.y + hv.z * hv.z + hv.w * hv.w;
    float tot = block_sum256(ss, red);
    float rs = rsqrtf(tot / (float)D_ + 1e-6f);
    float4 sc = *(const float4*)&nmod[b * 3072 + n];
    float4 sh = *(const float4*)&nmod[b * 3072 + 1024 + n];
    ushort4 o;
    o.x = f2bf(hv.x * rs * (1.f + sc.x) + sh.x);
    o.y = f2bf(hv.y * rs * (1.f + sc.y) + sh.y);
    o.z = f2bf(hv.z * rs * (1.f + sc.z) + sh.z);
    o.w = f2bf(hv.w * rs * (1.f + sc.w) + sh.w);
    *(ushort4*)&normed[(size_t)m * D_ + n] = o;
}

// ---------------- gate/up finish: act(bf16) = gelu_tanh(g) * u, KT=2 partials ----------------
__global__ __launch_bounds__(256) void k_gufin(const float* __restrict__ part, unsigned short* __restrict__ act) {
    int idx = blockIdx.x * 256 + threadIdx.x;   // 102400
    int e0 = idx * 4;
    int m = e0 / F_, f = e0 % F_;
    float4 g = make_float4(0.f, 0.f, 0.f, 0.f), u = make_float4(0.f, 0.f, 0.f, 0.f);
    #pragma unroll
    for (int kt = 0; kt < 2; kt++) {
        const float* base = &part[((size_t)kt * M_ + m) * 8192];
        float4 pg = *(const float4*)&base[f];
        float4 pu = *(const float4*)&base[4096 + f];
        g.x += pg.x; g.y += pg.y; g.z += pg.z; g.w += pg.w;
        u.x += pu.x; u.y += pu.y; u.z += pu.z; u.w += pu.w;
    }
    float gv[4] = {g.x, g.y, g.z, g.w};
    float uv[4] = {u.x, u.y, u.z, u.w};
    ushort4 o;
    unsigned short* op = (unsigned short*)&o;
    #pragma unroll
    for (int j = 0; j < 4; j++) {
        float x = gv[j];
        float t = tanhf(0.7978845608028654f * (x + 0.044715f * x * x * x));
        op[j] = f2bf(0.5f * x * (1.f + t) * uv[j]);
    }
    *(ushort4*)&act[(size_t)m * F_ + f] = o;
}

// ---------------- final projection: out = normed_f(bf16) @ w_act_out + b ----------------
__global__ __launch_bounds__(256) void k_final(const unsigned short* __restrict__ normed, const float* __restrict__ w,
                                               const float* __restrict__ bias, float* __restrict__ out) {
    int gid = blockIdx.x * 256 + threadIdx.x;
    if (gid >= M_ * AD_) return;
    int m = gid >> 5, n = gid & 31;
    float acc = bias[n];
    for (int k = 0; k < D_; k++) acc += bf2f(normed[(size_t)m * D_ + k]) * w[(size_t)k * AD_ + n];
    out[gid] = acc;
}

// ---------------- host launch ----------------
extern "C" void kernel_launch(void* const* d_in, const int* in_sizes, int n_in,
                              void* d_out, int out_size, void* d_ws, size_t ws_size,
                              hipStream_t stream) {
    (void)in_sizes; (void)n_in; (void)out_size; (void)ws_size;
    const float* x_t   = (const float*)d_in[1];
    const float* tstep = (const float*)d_in[2];
    const float* ck    = (const float*)d_in[3];
    const float* cv    = (const float*)d_in[4];
    const float* w_ti  = (const float*)d_in[5];
    const float* b_ti  = (const float*)d_in[6];
    const float* w_to  = (const float*)d_in[7];
    const float* b_to  = (const float*)d_in[8];
    const float* w_ai  = (const float*)d_in[9];
    const float* b_ai  = (const float*)d_in[10];
    const float* w_ao  = (const float*)d_in[11];
    const float* b_ao  = (const float*)d_in[12];
    const float* wq    = (const float*)d_in[13];
    const float* wk    = (const float*)d_in[14];
    const float* wv    = (const float*)d_in[15];
    const float* wo    = (const float*)d_in[16];
    const float* wg    = (const float*)d_in[17];
    const float* wu    = (const float*)d_in[18];
    const float* wd    = (const float*)d_in[19];
    const float* wn1   = (const float*)d_in[20];
    const float* wn2   = (const float*)d_in[21];
    const float* wnf   = (const float*)d_in[22];

    float* ws = (float*)d_ws;
    float* mods   = ws;                 // 79872
    float* cond   = ws + 79872;         // 2048
    float* temb   = ws + 81920;         // 2048
    float* ubuf   = ws + 83968;         // 2048
    float* hbuf   = ws + 86016;         // 102400
    float* qb     = ws + 188416;        // 204800
    float* kb     = ws + 393216;        // 204800
    float* vb     = ws + 598016;        // 204800
    float* opart  = ws + 802816;        // 3481600
    float* mlb    = ws + 4284416;       // 27200
    float* part   = ws + 4311616;       // up to 1638400
    unsigned short* normed_bf = (unsigned short*)(ws + 5950016);   // 100x1024 bf16
    unsigned short* attno_bf  = (unsigned short*)(ws + 6001216);   // 100x2048 bf16
    unsigned short* act_bf    = (unsigned short*)(ws + 6103616);   // 100x4096 bf16
    // end: 6308416 floats = 25.2 MB

    hipMemsetAsync(mods, 0, (size_t)13 * 6144 * sizeof(float), stream);
    k_temb<<<8, 256, 0, stream>>>(tstep, temb);
    k_gemv_silu<<<16, 256, 0, stream>>>(temb, w_ti, b_ti, ubuf);
    k_gemv_silu<<<16, 256, 0, stream>>>(ubuf, w_to, b_to, cond);
    k_mods<<<dim3(48, 13, 4), 256, 0, stream>>>(cond, wn1, wn2, wnf, mods);
    k_hinit<<<100, 256, 0, stream>>>(x_t, w_ai, b_ai, mods, hbuf, normed_bf);

    for (int l = 0; l < L_; l++) {
        // QKV: N=6144, K=1024, Ksplit=512 (kt=2)
        k_gemm_bf<2048><<<dim3(48, 1, 2), 256, 0, stream>>>(normed_bf, 1024, 512,
            wq + (size_t)l * 2097152, wk + (size_t)l * 2097152, wv + (size_t)l * 2097152, 6144, part);
        k_qkv_fin<<<600, 256, 0, stream>>>(part, qb, kb, vb);
        k_flash<<<dim3(NC_, 16), 256, 0, stream>>>(ck + (size_t)l * 4194304, cv + (size_t)l * 4194304,
            qb, kb, vb, opart, (float2*)mlb);
        k_att_combine<<<dim3(16, 5), 256, 0, stream>>>(opart, (const float2*)mlb, attno_bf);
        // O: N=1024, K=2048, Ksplit=512 (kt=4)
        k_gemm_bf<1024><<<dim3(8, 1, 4), 256, 0, stream>>>(attno_bf, 2048, 512,
            wo + (size_t)l * 2097152, nullptr, nullptr, 1024, part);
        k_resfin<<<100, 256, 0, stream>>>(part, 4, mods + l * 6144, mods + (6 + l) * 6144, hbuf, normed_bf);
        // Gate/Up: N=8192, K=1024, Ksplit=512 (kt=2)
        k_gemm_bf<4096><<<dim3(64, 1, 2), 256, 0, stream>>>(normed_bf, 1024, 512,
            wg + (size_t)l * 4194304, wu + (size_t)l * 4194304, nullptr, 8192, part);
        k_gufin<<<400, 256, 0, stream>>>(part, act_bf);
        // Down: N=1024, K=4096, Ksplit=512 (kt=8)
        k_gemm_bf<1024><<<dim3(8, 1, 8), 256, 0, stream>>>(act_bf, 4096, 512,
            wd + (size_t)l * 4194304, nullptr, nullptr, 1024, part);
        k_resfin<<<100, 256, 0, stream>>>(part, 8, mods + (6 + l) * 6144,
            mods + ((l == 5) ? 12 : (l + 1)) * 6144, hbuf, normed_bf);
    }
    k_final<<<13, 256, 0, stream>>>(normed_bf, w_ao, b_ao, (float*)d_out);
}